// Round 5
// baseline (151.689 us; speedup 1.0000x reference)
//
#include <hip/hip_runtime.h>
#include <math.h>

#define N_NODES 1024
#define N_EVAL 131072
#define NUM_POLES 8
#define PI_D 3.14159265358979323846

// ws layout: float4 pk[1024] = (node, w, w*v, 0) per node.
//
// Closed-form barycentric weights for Chebyshev points of the 2nd kind
// x_j = cos(pi*j/n), n = N_NODES-1:
//   1 / prod_{i!=j}(x_j - x_i) = (-1)^j * delta_j * 2^(n-1)/n, delta=1/2 at ends.
// Uniform positive scalings (2^(n-1)/n, exp(-max), /|w[0]|) cancel in num/den:
//   w_j = (-1)^j * delta_j * prod_m((x_j - pr_m)^2 + pi_m^2)
__global__ void wk_setup(const float* __restrict__ values,
                         const float* __restrict__ poles_real,
                         const float* __restrict__ poles_imag,
                         float4* __restrict__ pk) {
    const int j = blockIdx.x * 128 + threadIdx.x;
    const double nd = cos(PI_D * (double)j / (double)(N_NODES - 1));
    double prod = (j == 0 || j == N_NODES - 1) ? 0.5 : 1.0;
#pragma unroll
    for (int m = 0; m < NUM_POLES; ++m) {
        double dr = nd - (double)poles_real[m];
        double di = (double)poles_imag[m];
        prod *= dr * dr + di * di;
    }
    if (j & 1) prod = -prod;
    pk[j] = make_float4((float)nd, (float)prod,
                        (float)(prod * (double)values[j]), 0.0f);
}

typedef float f16v __attribute__((ext_vector_type(16)));

// Eval: block = 4 waves, 64 points/block (point = lane). Wave w streams node
// chunk [w*256, w*256+256) through SGPRs via s_load_dwordx16 (node data is
// wave-uniform -> scalar pipe; zero LDS / zero vector loads in the loop;
// every VALU op reads at most 1 SGPR). The chunk pointer is laundered through
// readfirstlane so the compiler provably sees it as uniform (R4 compile fix).
// Partial num/den combined via a tiny LDS reduction. Batched reciprocal
// r=rcp(dA*dB) halves trans-pipe pressure. Exact node hits (d==0) poison
// accumulators with inf/NaN -> rare global-scan fix-up (reference semantics:
// exact-hit column reduces to sum(hit wv)/sum(hit w)).
__global__ __launch_bounds__(256, 8) void eval_kernel(
    const float* __restrict__ x_eval,
    const float4* __restrict__ pk,
    float* __restrict__ out) {
    const int lane = threadIdx.x & 63;
    const int wid  = threadIdx.x >> 6;  // wave id 0..3 -> node chunk
    const int p = blockIdx.x * 64 + lane;
    const float x = x_eval[p];

    // Wave-uniform chunk pointer, forced into SGPRs.
    unsigned long long up = (unsigned long long)(pk + wid * 256);
    const unsigned lo = __builtin_amdgcn_readfirstlane((unsigned int)up);
    const unsigned hi = __builtin_amdgcn_readfirstlane((unsigned int)(up >> 32));
    const float4* tp = (const float4*)((((unsigned long long)hi) << 32) | lo);

    float num0 = 0.0f, den0 = 0.0f;
    float num1 = 0.0f, den1 = 0.0f;

#define PAIR(nA, wA, vA, nB, wB, vB, NUM, DEN)                             \
    {                                                                      \
        const float dA = x - (nA);                                         \
        const float dB = x - (nB);                                         \
        const float pp = dA * dB;                                          \
        const float r = __builtin_amdgcn_rcpf(pp);                         \
        const float rA = r * dB;                                           \
        const float rB = r * dA;                                           \
        NUM = fmaf((vA), rA, NUM);                                         \
        DEN = fmaf((wA), rA, DEN);                                         \
        NUM = fmaf((vB), rB, NUM);                                         \
        DEN = fmaf((wB), rB, DEN);                                         \
    }

    for (int it = 0; it < 32; ++it) {
        f16v ta, tb;
        asm volatile(
            "s_load_dwordx16 %0, %2, 0x0\n\t"
            "s_load_dwordx16 %1, %2, 0x40\n\t"
            "s_waitcnt lgkmcnt(0)"
            : "=&s"(ta), "=&s"(tb)
            : "s"(tp));
        // ta: nodes 0..3, tb: nodes 4..7; element k: n=t[4k],w=t[4k+1],v=t[4k+2]
        PAIR(ta[0], ta[1], ta[2], ta[4], ta[5], ta[6], num0, den0)
        PAIR(ta[8], ta[9], ta[10], ta[12], ta[13], ta[14], num1, den1)
        PAIR(tb[0], tb[1], tb[2], tb[4], tb[5], tb[6], num0, den0)
        PAIR(tb[8], tb[9], tb[10], tb[12], tb[13], tb[14], num1, den1)
        tp += 8;
    }
#undef PAIR

    __shared__ float rn[4][64];
    __shared__ float rd[4][64];
    rn[wid][lane] = num0 + num1;
    rd[wid][lane] = den0 + den1;
    __syncthreads();

    if (wid == 0) {
        const float nn = (rn[0][lane] + rn[1][lane]) + (rn[2][lane] + rn[3][lane]);
        const float dd = (rd[0][lane] + rd[1][lane]) + (rd[2][lane] + rd[3][lane]);
        float res = nn / dd;
        if (__builtin_expect(__builtin_isnan(res), 0)) {
            float hn = 0.0f, hd = 0.0f;
            for (int j = 0; j < N_NODES; ++j) {
                const float4 e = pk[j];
                if (e.x == x) { hn += e.z; hd += e.y; }
            }
            res = hn / hd;
        }
        out[p] = res;
    }
}

extern "C" void kernel_launch(void* const* d_in, const int* in_sizes, int n_in,
                              void* d_out, int out_size, void* d_ws, size_t ws_size,
                              hipStream_t stream) {
    const float* x_eval     = (const float*)d_in[0];
    const float* values     = (const float*)d_in[1];
    const float* poles_real = (const float*)d_in[2];
    const float* poles_imag = (const float*)d_in[3];
    float* out = (float*)d_out;

    float4* pk = (float4*)d_ws;

    wk_setup<<<8, 128, 0, stream>>>(values, poles_real, poles_imag, pk);
    eval_kernel<<<N_EVAL / 64, 256, 0, stream>>>(x_eval, pk, out);
}

// Round 6
// 125.903 us; speedup vs baseline: 1.2048x; 1.2048x over previous
//
#include <hip/hip_runtime.h>
#include <math.h>

#define N_NODES 1024
#define N_EVAL 131072
#define NUM_POLES 8
#define PI_D 3.14159265358979323846

// Single fused kernel. Block = 512 threads = 8 waves; 256 points per block;
// grid 512 blocks = 2 blocks/CU = 4 waves/SIMD.
//
// Phase 1: closed-form barycentric weights, computed redundantly per block
// (cheap: 2 nodes/thread, double precision) straight into LDS. For Chebyshev
// points of the 2nd kind x_j = cos(pi*j/n), n = N_NODES-1:
//   1/prod_{i!=j}(x_j-x_i) = (-1)^j * delta_j * 2^(n-1)/n, delta=1/2 at ends.
// Uniform positive scalings (2^(n-1)/n, exp(-max), /|w[0]|) cancel in
// num/den, so: w_j = (-1)^j * delta_j * prod_m((x_j-pr_m)^2 + pi_m^2).
//
// Phase 2: wave w sums its 128-node chunk for the block's 256 points
// (4 points/thread -> LDS broadcast reads amortized 4x, 4 independent FMA
// chains for ILP). Plain v_rcp_f32, no Newton (~1 ulp, trans pipe is not
// the wall). Exact node hits (d==0) poison accumulators with inf/NaN.
//
// Phase 3: reduce the 8 wave-partials per point, divide, rare NaN fix-up
// (reference: exact-hit column reduces to sum(hit wv)/sum(hit w)).
__global__ __launch_bounds__(512, 4) void eval_kernel(
    const float* __restrict__ x_eval,
    const float* __restrict__ values,
    const float* __restrict__ poles_real,
    const float* __restrict__ poles_imag,
    float* __restrict__ out) {
    __shared__ __align__(16) float s_n[N_NODES];
    __shared__ __align__(16) float s_w[N_NODES];
    __shared__ __align__(16) float s_v[N_NODES];
    __shared__ float2 s_r[8][256];

    const int t = threadIdx.x;

    // ---- Phase 1: weights -> LDS ----
#pragma unroll
    for (int h = 0; h < 2; ++h) {
        const int j = t + h * 512;
        const double nd = cos(PI_D * (double)j / (double)(N_NODES - 1));
        double prod = (j == 0 || j == N_NODES - 1) ? 0.5 : 1.0;
#pragma unroll
        for (int m = 0; m < NUM_POLES; ++m) {
            const double dr = nd - (double)poles_real[m];
            const double di = (double)poles_imag[m];
            prod *= dr * dr + di * di;
        }
        if (j & 1) prod = -prod;
        s_n[j] = (float)nd;
        s_w[j] = (float)prod;
        s_v[j] = (float)(prod * (double)values[j]);
    }
    __syncthreads();

    // ---- Phase 2: per-wave 128-node chunk, 4 points/thread ----
    const int lane = t & 63;
    const int wid  = t >> 6;
    const int pbase = blockIdx.x * 256;
    const float x0 = x_eval[pbase + lane];
    const float x1 = x_eval[pbase + 64 + lane];
    const float x2 = x_eval[pbase + 128 + lane];
    const float x3 = x_eval[pbase + 192 + lane];

    const float4* n4 = (const float4*)s_n + wid * 32;
    const float4* w4 = (const float4*)s_w + wid * 32;
    const float4* v4 = (const float4*)s_v + wid * 32;

    float a0 = 0.0f, b0 = 0.0f, a1 = 0.0f, b1 = 0.0f;
    float a2 = 0.0f, b2 = 0.0f, a3 = 0.0f, b3 = 0.0f;

#define NODE(C)                                                            \
    {                                                                      \
        const float d0 = x0 - an.C;                                        \
        const float d1 = x1 - an.C;                                        \
        const float d2 = x2 - an.C;                                        \
        const float d3 = x3 - an.C;                                        \
        const float r0 = __builtin_amdgcn_rcpf(d0);                        \
        const float r1 = __builtin_amdgcn_rcpf(d1);                        \
        const float r2 = __builtin_amdgcn_rcpf(d2);                        \
        const float r3 = __builtin_amdgcn_rcpf(d3);                        \
        a0 = fmaf(av.C, r0, a0); b0 = fmaf(aw.C, r0, b0);                  \
        a1 = fmaf(av.C, r1, a1); b1 = fmaf(aw.C, r1, b1);                  \
        a2 = fmaf(av.C, r2, a2); b2 = fmaf(aw.C, r2, b2);                  \
        a3 = fmaf(av.C, r3, a3); b3 = fmaf(aw.C, r3, b3);                  \
    }

#pragma unroll 4
    for (int q = 0; q < 32; ++q) {
        const float4 an = n4[q];
        const float4 aw = w4[q];
        const float4 av = v4[q];
        NODE(x) NODE(y) NODE(z) NODE(w)
    }
#undef NODE

    s_r[wid][lane]       = make_float2(a0, b0);
    s_r[wid][lane + 64]  = make_float2(a1, b1);
    s_r[wid][lane + 128] = make_float2(a2, b2);
    s_r[wid][lane + 192] = make_float2(a3, b3);
    __syncthreads();

    // ---- Phase 3: reduce 8 wave-partials, divide, fix exact hits ----
    if (t < 256) {
        float nn = 0.0f, dd = 0.0f;
#pragma unroll
        for (int w = 0; w < 8; ++w) {
            const float2 pr = s_r[w][t];
            nn += pr.x;
            dd += pr.y;
        }
        float res = nn / dd;
        if (__builtin_expect(__builtin_isnan(res), 0)) {
            const float x = x_eval[pbase + t];
            float hn = 0.0f, hd = 0.0f;
            for (int j = 0; j < N_NODES; ++j) {
                if (s_n[j] == x) { hn += s_v[j]; hd += s_w[j]; }
            }
            res = hn / hd;
        }
        out[pbase + t] = res;
    }
}

extern "C" void kernel_launch(void* const* d_in, const int* in_sizes, int n_in,
                              void* d_out, int out_size, void* d_ws, size_t ws_size,
                              hipStream_t stream) {
    const float* x_eval     = (const float*)d_in[0];
    const float* values     = (const float*)d_in[1];
    const float* poles_real = (const float*)d_in[2];
    const float* poles_imag = (const float*)d_in[3];
    float* out = (float*)d_out;

    eval_kernel<<<N_EVAL / 256, 512, 0, stream>>>(x_eval, values,
                                                  poles_real, poles_imag, out);
}